// Round 2
// baseline (274.751 us; speedup 1.0000x reference)
//
#include <hip/hip_runtime.h>
#include <hip/hip_bf16.h>

// StochasticEnsemble: hard-routed 8-expert MLP.
// Round 2: B-resident-in-LDS GEMMs. Grid = (n_tile, expert); each block stages
// its expert's W-slab ONCE into LDS (fragment-chunk layout, conflict-free b128
// on both sides), then loops over the expert's M-tiles with a barrier-free
// K-loop (A fragments straight from global). W2 is fetched exactly once.

#define BATCH 2048
#define ZD 128
#define HID 1024
#define OUTD 3072
#define NEXP 8
#define TM 64
#define TN 32
#define MAXROWS (BATCH + NEXP * TM)   // 2560 padded gathered rows max
#define MAXT (MAXROWS / TM)

typedef short bf16x8 __attribute__((ext_vector_type(8)));   // 8 bf16 = 4 VGPRs
typedef float f32x4 __attribute__((ext_vector_type(4)));

// ---- workspace byte layout ----
// 0      counts[8]
// 64     ntiles (1 int, informational)
// 128    tstart[8]
// 192    tcnt[8]
// 512    perm[MAXROWS]
// 10752  bucket[8*2048]
// 76288  H bf16 [MAXROWS * HID]   (16B aligned)

__global__ __launch_bounds__(256) void route_kernel(const float* __restrict__ z,
                                                    int* counts, int* bucket) {
    int gid = blockIdx.x * 256 + threadIdx.x;
    int s_idx = gid >> 6;      // one wave per sample
    int lane = gid & 63;
    float a = z[s_idx * ZD + lane];
    float b = z[s_idx * ZD + 64 + lane];
    float s = floorf(fabsf(a) * 1000.0f) + floorf(fabsf(b) * 1000.0f);
#pragma unroll
    for (int off = 32; off > 0; off >>= 1) s += __shfl_down(s, off);
    if (lane == 0) {
        int e = ((int)s) & 7;
        int pos = atomicAdd(&counts[e], 1);
        bucket[e * BATCH + pos] = s_idx;
    }
}

__global__ void scan_kernel(const int* __restrict__ counts, int* ntiles,
                            int* tstart, int* tcnt, int* perm,
                            const int* __restrict__ bucket) {
    __shared__ int soff[NEXP + 1];
    __shared__ int scnt[NEXP];
    if (threadIdx.x == 0) {
        int o = 0;
        for (int e = 0; e < NEXP; e++) {
            scnt[e] = counts[e];
            soff[e] = o;
            tstart[e] = o / TM;
            int t = (scnt[e] + TM - 1) / TM;
            tcnt[e] = t;
            o += t * TM;
        }
        soff[NEXP] = o;
        *ntiles = o / TM;
    }
    __syncthreads();
    int total = soff[NEXP];
    for (int r = threadIdx.x; r < total; r += blockDim.x) {
        int e = 0;
        while (r >= soff[e + 1]) e++;
        int i = r - soff[e];
        perm[r] = (i < scnt[e]) ? bucket[e * BATCH + i] : -1;
    }
}

// GEMM1: H[mt*64+m, n] = relu(z[perm] @ W1[e] + b1[e]).  K=128, N=1024, TN=32.
__global__ __launch_bounds__(256, 2) void gemm1_kernel(
    const float* __restrict__ z, const float* __restrict__ W1,
    const float* __restrict__ b1, const int* __restrict__ tstart,
    const int* __restrict__ tcnt, const int* __restrict__ perm,
    __hip_bfloat16* __restrict__ H) {
    int e = blockIdx.y;
    int tc = tcnt[e];
    if (tc == 0) return;
    int ts = tstart[e];
    int n0 = blockIdx.x * TN;

    // chunk (ko, n): 8 bf16 = W1[e][ko*8 .. +7][n0+n];  ko in [0,16), n in [0,32)
    __shared__ __align__(16) __hip_bfloat16 Bs[(ZD / 8) * TN * 8];   // 8 KB
    __shared__ int rows_s[TM];

    int tid = threadIdx.x;
    const float* W = W1 + (size_t)e * ZD * HID;
#pragma unroll
    for (int i = 0; i < 2; ++i) {
        int ko = i * 8 + (tid >> 5);
        int n = tid & 31;
        union { bf16x8 v8; __hip_bfloat16 h[8]; } u;
#pragma unroll
        for (int j = 0; j < 8; ++j)
            u.h[j] = __float2bfloat16(W[(size_t)(ko * 8 + j) * HID + n0 + n]);
        *(bf16x8*)((char*)Bs + (size_t)(ko * TN + n) * 16) = u.v8;
    }

    int lane = tid & 63, wave = tid >> 6;
    int mw = wave * 16;            // 4 waves x 16-row strips = TM 64
    int cc = lane & 15, q = lane >> 4;
    float bias0 = b1[(size_t)e * HID + n0 + cc];
    float bias1 = b1[(size_t)e * HID + n0 + 16 + cc];
    __syncthreads();

    for (int mi = 0; mi < tc; ++mi) {
        int mt = ts + mi;
        __syncthreads();                       // rows_s reuse guard
        if (tid < TM) rows_s[tid] = perm[mt * TM + tid];
        __syncthreads();
        int arow = rows_s[mw + cc];
        const float* zp = z + (size_t)(arow < 0 ? 0 : arow) * ZD + q * 8;
        f32x4 acc0 = {0.f, 0.f, 0.f, 0.f}, acc1 = acc0;
#pragma unroll
        for (int s = 0; s < ZD / 32; ++s) {
            float4 v0 = ((const float4*)(zp + s * 32))[0];
            float4 v1 = ((const float4*)(zp + s * 32))[1];
            float v[8] = {v0.x, v0.y, v0.z, v0.w, v1.x, v1.y, v1.z, v1.w};
            union { bf16x8 v8; __hip_bfloat16 h[8]; } u;
#pragma unroll
            for (int j = 0; j < 8; ++j)
                u.h[j] = __float2bfloat16(arow < 0 ? 0.f : v[j]);
            bf16x8 b0 = *(const bf16x8*)((char*)Bs + (size_t)((s * 4 + q) * TN + cc) * 16);
            bf16x8 b1v = *(const bf16x8*)((char*)Bs + (size_t)((s * 4 + q) * TN + 16 + cc) * 16);
            acc0 = __builtin_amdgcn_mfma_f32_16x16x32_bf16(u.v8, b0, acc0, 0, 0, 0);
            acc1 = __builtin_amdgcn_mfma_f32_16x16x32_bf16(u.v8, b1v, acc1, 0, 0, 0);
        }
#pragma unroll
        for (int r = 0; r < 4; ++r) {
            int m = mw + q * 4 + r;
            size_t hb = (size_t)(mt * TM + m) * HID + n0;
            H[hb + cc] = __float2bfloat16(fmaxf(acc0[r] + bias0, 0.f));
            H[hb + 16 + cc] = __float2bfloat16(fmaxf(acc1[r] + bias1, 0.f));
        }
    }
}

// GEMM2: out[perm] = H @ W2[e] + b2[e].  K=1024, N=3072, TN=32.
// B slab 64 KB resident in LDS; K-loop has zero barriers.
__global__ __launch_bounds__(256, 2) void gemm2_kernel(
    const __hip_bfloat16* __restrict__ H, const float* __restrict__ W2,
    const float* __restrict__ b2, const int* __restrict__ tstart,
    const int* __restrict__ tcnt, const int* __restrict__ perm,
    float* __restrict__ out) {
    int e = blockIdx.y;
    int tc = tcnt[e];
    if (tc == 0) return;
    int ts = tstart[e];
    int n0 = blockIdx.x * TN;

    // chunk (ko, n): 8 bf16 = W2[e][ko*8 .. +7][n0+n];  ko in [0,128), n in [0,32)
    __shared__ __align__(16) __hip_bfloat16 Bs[(HID / 8) * TN * 8];   // 64 KB
    __shared__ int rows_s[TM];

    int tid = threadIdx.x;
    const float* W = W2 + (size_t)e * HID * OUTD;
#pragma unroll 4
    for (int i = 0; i < 16; ++i) {
        int ko = i * 8 + (tid >> 5);
        int n = tid & 31;
        union { bf16x8 v8; __hip_bfloat16 h[8]; } u;
#pragma unroll
        for (int j = 0; j < 8; ++j)
            u.h[j] = __float2bfloat16(W[(size_t)(ko * 8 + j) * OUTD + n0 + n]);
        *(bf16x8*)((char*)Bs + (size_t)(ko * TN + n) * 16) = u.v8;
    }

    int lane = tid & 63, wave = tid >> 6;
    int mw = wave * 16;
    int cc = lane & 15, q = lane >> 4;
    float bias0 = b2[(size_t)e * OUTD + n0 + cc];
    float bias1 = b2[(size_t)e * OUTD + n0 + 16 + cc];
    __syncthreads();

    for (int mi = 0; mi < tc; ++mi) {
        int mt = ts + mi;
        __syncthreads();                       // rows_s reuse guard
        if (tid < TM) rows_s[tid] = perm[mt * TM + tid];
        __syncthreads();
        const __hip_bfloat16* Ab = H + (size_t)(mt * TM + mw + cc) * HID + q * 8;
        f32x4 acc0 = {0.f, 0.f, 0.f, 0.f}, acc1 = acc0;
#pragma unroll 8
        for (int s = 0; s < HID / 32; ++s) {
            bf16x8 af = *(const bf16x8*)(Ab + s * 32);
            bf16x8 b0 = *(const bf16x8*)((char*)Bs + (size_t)((s * 4 + q) * TN + cc) * 16);
            bf16x8 b1v = *(const bf16x8*)((char*)Bs + (size_t)((s * 4 + q) * TN + 16 + cc) * 16);
            acc0 = __builtin_amdgcn_mfma_f32_16x16x32_bf16(af, b0, acc0, 0, 0, 0);
            acc1 = __builtin_amdgcn_mfma_f32_16x16x32_bf16(af, b1v, acc1, 0, 0, 0);
        }
#pragma unroll
        for (int r = 0; r < 4; ++r) {
            int m = mw + q * 4 + r;
            int orow = rows_s[m];
            if (orow >= 0) {
                size_t ob = (size_t)orow * OUTD + n0;
                out[ob + cc] = acc0[r] + bias0;
                out[ob + 16 + cc] = acc1[r] + bias1;
            }
        }
    }
}

extern "C" void kernel_launch(void* const* d_in, const int* in_sizes, int n_in,
                              void* d_out, int out_size, void* d_ws, size_t ws_size,
                              hipStream_t stream) {
    const float* z  = (const float*)d_in[0];
    const float* W1 = (const float*)d_in[1];
    const float* b1 = (const float*)d_in[2];
    const float* W2 = (const float*)d_in[3];
    const float* b2 = (const float*)d_in[4];
    float* out = (float*)d_out;

    char* ws = (char*)d_ws;
    int* counts = (int*)ws;
    int* ntl    = (int*)(ws + 64);
    int* tstart = (int*)(ws + 128);
    int* tcnt   = (int*)(ws + 192);
    int* perm   = (int*)(ws + 512);
    int* bucket = (int*)(ws + 10752);
    __hip_bfloat16* H = (__hip_bfloat16*)(ws + 76288);   // 5.25 MB

    hipMemsetAsync(counts, 0, 64, stream);
    hipLaunchKernelGGL(route_kernel, dim3(BATCH / 4), dim3(256), 0, stream,
                       z, counts, bucket);
    hipLaunchKernelGGL(scan_kernel, dim3(1), dim3(256), 0, stream,
                       counts, ntl, tstart, tcnt, perm, bucket);
    hipLaunchKernelGGL(gemm1_kernel, dim3(HID / TN, NEXP), dim3(256), 0, stream,
                       z, W1, b1, tstart, tcnt, perm, H);
    hipLaunchKernelGGL(gemm2_kernel, dim3(OUTD / TN, NEXP), dim3(256), 0, stream,
                       H, W2, b2, tstart, tcnt, perm, out);
}

// Round 3
// 236.703 us; speedup vs baseline: 1.1607x; 1.1607x over previous
//
#include <hip/hip_runtime.h>
#include <hip/hip_bf16.h>

// StochasticEnsemble: hard-routed 8-expert MLP.
// Round 3: preprocess (transpose+convert weights to bf16 [e][n][k]) once per
// launch, then run both GEMMs in the m97-verified shape: 128x128 tile, BK=64,
// both operands k-contiguous bf16, XOR-swizzled LDS (conflict-free b128 both
// sides), register-prefetch single-buffer K-loop, 4x4 MFMA frags per wave.
// Fallback to round-2 kernels if ws_size < 59.3 MB.

#define BATCH 2048
#define ZD 128
#define HID 1024
#define OUTD 3072
#define NEXP 8

// fast-path gemm tile
#define TMG 128
#define TNG 128
#define BKG 64
#define MAXTF 24          // max 128-row M-tiles: 2048/128 + 7 = 23 <= 24

// fallback tile (round-2 kernels)
#define TM 64
#define TN 32

typedef short bf16x8 __attribute__((ext_vector_type(8)));   // 8 bf16 = 4 VGPRs
typedef float f32x4 __attribute__((ext_vector_type(4)));

// ---- shared control workspace layout (both paths) ----
// 0      counts[8]
// 64     ntl[1]
// 128    tstart[8]   (fallback)
// 192    tcnt[8]     (fallback)
// 256    texp[<=64]
// 512    perm[<=3072]            -> ends 12800
// fast path:
// 12800  bucket[8*2048]          -> ends 78336
// 78336  zb bf16 [2048*128]      -> ends 602624
// 602624 H bf16 [3072*1024]      -> ends 6894080
// 6894080 W1T bf16 [8*1024*128]  -> ends 8991232
// 8991232 W2T bf16 [8*3072*1024] -> ends 59322880
// fallback path: bucket at 10752, H at 76288 (round-2 layout)

__global__ __launch_bounds__(256) void route_kernel(const float* __restrict__ z,
                                                    int* counts, int* bucket) {
    int gid = blockIdx.x * 256 + threadIdx.x;
    int s_idx = gid >> 6;      // one wave per sample
    int lane = gid & 63;
    float a = z[s_idx * ZD + lane];
    float b = z[s_idx * ZD + 64 + lane];
    float s = floorf(fabsf(a) * 1000.0f) + floorf(fabsf(b) * 1000.0f);
#pragma unroll
    for (int off = 32; off > 0; off >>= 1) s += __shfl_down(s, off);
    if (lane == 0) {
        int e = ((int)s) & 7;
        int pos = atomicAdd(&counts[e], 1);
        bucket[e * BATCH + pos] = s_idx;
    }
}

__global__ void scan_kernel(const int* __restrict__ counts, int* ntl,
                            int* tstart, int* tcnt, int* texp, int* perm,
                            const int* __restrict__ bucket, int TMv) {
    __shared__ int soff[NEXP + 1];
    __shared__ int scnt[NEXP];
    if (threadIdx.x == 0) {
        int o = 0;
        for (int e = 0; e < NEXP; e++) {
            scnt[e] = counts[e];
            soff[e] = o;
            tstart[e] = o / TMv;
            int t = (scnt[e] + TMv - 1) / TMv;
            tcnt[e] = t;
            o += t * TMv;
        }
        soff[NEXP] = o;
        *ntl = o / TMv;
    }
    __syncthreads();
    int total = soff[NEXP];
    for (int r = threadIdx.x; r < total; r += blockDim.x) {
        int e = 0;
        while (r >= soff[e + 1]) e++;
        int i = r - soff[e];
        perm[r] = (i < scnt[e]) ? bucket[e * BATCH + i] : -1;
        if (r % TMv == 0) texp[r / TMv] = e;
    }
}

// z f32 -> bf16 (values only; routing uses exact f32 z)
__global__ __launch_bounds__(256) void convz_kernel(const float* __restrict__ z,
                                                    __hip_bfloat16* __restrict__ zb) {
    int idx = blockIdx.x * 256 + threadIdx.x;        // one float4 per thread
    float4 v = ((const float4*)z)[idx];
    union { uint2 u; __hip_bfloat16 h[4]; } o;
    o.h[0] = __float2bfloat16(v.x);
    o.h[1] = __float2bfloat16(v.y);
    o.h[2] = __float2bfloat16(v.z);
    o.h[3] = __float2bfloat16(v.w);
    ((uint2*)zb)[idx] = o.u;
}

// W[e][K][N] f32 (n-contig) -> WT[e][N][K] bf16 (k-contig), 64x64 tiles via LDS
__global__ __launch_bounds__(256) void trans_kernel(const float* __restrict__ W,
                                                    __hip_bfloat16* __restrict__ WT,
                                                    int K, int N) {
    int e = blockIdx.z;
    int n0 = blockIdx.x * 64;
    int k0 = blockIdx.y * 64;
    const float* Wp = W + (size_t)e * K * N;
    __hip_bfloat16* Op = WT + (size_t)e * N * K;
    __shared__ __hip_bfloat16 Ts[64][68];
    int t = threadIdx.x;
    int kk = t >> 4, nn = (t & 15) * 4;
#pragma unroll
    for (int i = 0; i < 4; i++) {
        int k = i * 16 + kk;
        float4 v = *(const float4*)(Wp + (size_t)(k0 + k) * N + n0 + nn);
        Ts[k][nn + 0] = __float2bfloat16(v.x);
        Ts[k][nn + 1] = __float2bfloat16(v.y);
        Ts[k][nn + 2] = __float2bfloat16(v.z);
        Ts[k][nn + 3] = __float2bfloat16(v.w);
    }
    __syncthreads();
    int n = t >> 2;
#pragma unroll
    for (int p = 0; p < 2; p++) {
        int ch = p * 4 + (t & 3);
        union { bf16x8 v; __hip_bfloat16 h[8]; } u;
#pragma unroll
        for (int j = 0; j < 8; j++) u.h[j] = Ts[ch * 8 + j][n];
        *(bf16x8*)(Op + (size_t)(n0 + n) * K + k0 + ch * 8) = u.v;
    }
}

// ---------------- fast GEMMs (m97 shape) ----------------
// LDS tile layout: 16B chunk c of row r stored at elem ((r*8) + (c ^ (r&7)))*8.
// Staging writes and fragment reads are both b128 and conflict-free (<=2-way).

__global__ __launch_bounds__(256, 3) void gemm1_fast(
    const __hip_bfloat16* __restrict__ zb, const __hip_bfloat16* __restrict__ W1T,
    const float* __restrict__ b1, const int* __restrict__ ntl,
    const int* __restrict__ texp, const int* __restrict__ perm,
    __hip_bfloat16* __restrict__ H) {
    int mt = blockIdx.y;
    if (mt >= *ntl) return;
    int e = texp[mt];
    int n0 = blockIdx.x * TNG;

    __shared__ __align__(16) __hip_bfloat16 As[TMG * BKG];
    __shared__ __align__(16) __hip_bfloat16 Bs[TNG * BKG];
    __shared__ int rows_s[TMG];

    int tid = threadIdx.x;
    if (tid < TMG) rows_s[tid] = perm[mt * TMG + tid];
    __syncthreads();

    int lane = tid & 63, wave = tid >> 6;
    int cc = lane & 15, q = lane >> 4;
    int mw = (wave >> 1) * 64, nw = (wave & 1) * 64;

    int sr = tid >> 3, sc = tid & 7;
    int wbase = sr * 64 + (sc ^ (sr & 7)) * 8;     // + p*2048
    const __hip_bfloat16* Bg = W1T + ((size_t)e * HID + n0 + sr) * ZD + sc * 8;
    const __hip_bfloat16* Arp[4];
#pragma unroll
    for (int p = 0; p < 4; p++) {
        int r = rows_s[p * 32 + sr];
        if (r < 0) r = 0;
        Arp[p] = zb + (size_t)r * ZD + sc * 8;
    }

    int A0 = (mw + cc) * 64, B0 = (nw + cc) * 64;
    int X0 = (q ^ (cc & 7)) * 8, X1 = ((4 + q) ^ (cc & 7)) * 8;

    float bias[4];
#pragma unroll
    for (int j = 0; j < 4; j++) bias[j] = b1[(size_t)e * HID + n0 + nw + j * 16 + cc];

    f32x4 zero4 = {0.f, 0.f, 0.f, 0.f};
    f32x4 acc[4][4];
#pragma unroll
    for (int i = 0; i < 4; i++)
#pragma unroll
        for (int j = 0; j < 4; j++) acc[i][j] = zero4;

    bf16x8 ga[4], gb[4];
#pragma unroll
    for (int p = 0; p < 4; p++) {
        ga[p] = *(const bf16x8*)(Arp[p]);
        gb[p] = *(const bf16x8*)(Bg + (size_t)p * 32 * ZD);
    }
#pragma unroll
    for (int it = 0; it < ZD / BKG; ++it) {
        __syncthreads();
#pragma unroll
        for (int p = 0; p < 4; p++) {
            *(bf16x8*)(As + wbase + p * 2048) = ga[p];
            *(bf16x8*)(Bs + wbase + p * 2048) = gb[p];
        }
        __syncthreads();
        if (it + 1 < ZD / BKG) {
#pragma unroll
            for (int p = 0; p < 4; p++) {
                ga[p] = *(const bf16x8*)(Arp[p] + (it + 1) * BKG);
                gb[p] = *(const bf16x8*)(Bg + (size_t)p * 32 * ZD + (it + 1) * BKG);
            }
        }
#pragma unroll
        for (int kh = 0; kh < 2; ++kh) {
            int X = kh ? X1 : X0;
            bf16x8 af[4], bfr[4];
#pragma unroll
            for (int i = 0; i < 4; i++) af[i] = *(const bf16x8*)(As + A0 + i * 1024 + X);
#pragma unroll
            for (int j = 0; j < 4; j++) bfr[j] = *(const bf16x8*)(Bs + B0 + j * 1024 + X);
#pragma unroll
            for (int i = 0; i < 4; i++)
#pragma unroll
                for (int j = 0; j < 4; j++)
                    acc[i][j] = __builtin_amdgcn_mfma_f32_16x16x32_bf16(af[i], bfr[j],
                                                                        acc[i][j], 0, 0, 0);
        }
    }
#pragma unroll
    for (int i = 0; i < 4; i++)
#pragma unroll
        for (int r = 0; r < 4; r++) {
            int m = mw + i * 16 + q * 4 + r;
            __hip_bfloat16* hp = H + (size_t)(mt * TMG + m) * HID + n0 + nw + cc;
#pragma unroll
            for (int j = 0; j < 4; j++)
                hp[j * 16] = __float2bfloat16(fmaxf(acc[i][j][r] + bias[j], 0.f));
        }
}

__global__ __launch_bounds__(256, 3) void gemm2_fast(
    const __hip_bfloat16* __restrict__ H, const __hip_bfloat16* __restrict__ W2T,
    const float* __restrict__ b2, const int* __restrict__ ntl,
    const int* __restrict__ texp, const int* __restrict__ perm,
    float* __restrict__ out) {
    int mt = blockIdx.y;
    if (mt >= *ntl) return;
    int e = texp[mt];
    int n0 = blockIdx.x * TNG;

    __shared__ __align__(16) __hip_bfloat16 As[TMG * BKG];
    __shared__ __align__(16) __hip_bfloat16 Bs[TNG * BKG];
    __shared__ int rows_s[TMG];

    int tid = threadIdx.x;
    if (tid < TMG) rows_s[tid] = perm[mt * TMG + tid];

    int lane = tid & 63, wave = tid >> 6;
    int cc = lane & 15, q = lane >> 4;
    int mw = (wave >> 1) * 64, nw = (wave & 1) * 64;

    int sr = tid >> 3, sc = tid & 7;
    int wbase = sr * 64 + (sc ^ (sr & 7)) * 8;     // + p*2048
    const __hip_bfloat16* Ag = H + ((size_t)mt * TMG + sr) * HID + sc * 8;
    const __hip_bfloat16* Bg = W2T + ((size_t)e * OUTD + n0 + sr) * HID + sc * 8;

    int A0 = (mw + cc) * 64, B0 = (nw + cc) * 64;
    int X0 = (q ^ (cc & 7)) * 8, X1 = ((4 + q) ^ (cc & 7)) * 8;

    float bias[4];
#pragma unroll
    for (int j = 0; j < 4; j++) bias[j] = b2[(size_t)e * OUTD + n0 + nw + j * 16 + cc];

    f32x4 zero4 = {0.f, 0.f, 0.f, 0.f};
    f32x4 acc[4][4];
#pragma unroll
    for (int i = 0; i < 4; i++)
#pragma unroll
        for (int j = 0; j < 4; j++) acc[i][j] = zero4;

    bf16x8 ga[4], gb[4];
#pragma unroll
    for (int p = 0; p < 4; p++) {
        ga[p] = *(const bf16x8*)(Ag + (size_t)p * 32 * HID);
        gb[p] = *(const bf16x8*)(Bg + (size_t)p * 32 * HID);
    }
    for (int it = 0; it < HID / BKG; ++it) {
        __syncthreads();
#pragma unroll
        for (int p = 0; p < 4; p++) {
            *(bf16x8*)(As + wbase + p * 2048) = ga[p];
            *(bf16x8*)(Bs + wbase + p * 2048) = gb[p];
        }
        __syncthreads();
        if (it + 1 < HID / BKG) {
            int k1 = (it + 1) * BKG;
#pragma unroll
            for (int p = 0; p < 4; p++) {
                ga[p] = *(const bf16x8*)(Ag + (size_t)p * 32 * HID + k1);
                gb[p] = *(const bf16x8*)(Bg + (size_t)p * 32 * HID + k1);
            }
        }
#pragma unroll
        for (int kh = 0; kh < 2; ++kh) {
            int X = kh ? X1 : X0;
            bf16x8 af[4], bfr[4];
#pragma unroll
            for (int i = 0; i < 4; i++) af[i] = *(const bf16x8*)(As + A0 + i * 1024 + X);
#pragma unroll
            for (int j = 0; j < 4; j++) bfr[j] = *(const bf16x8*)(Bs + B0 + j * 1024 + X);
#pragma unroll
            for (int i = 0; i < 4; i++)
#pragma unroll
                for (int j = 0; j < 4; j++)
                    acc[i][j] = __builtin_amdgcn_mfma_f32_16x16x32_bf16(af[i], bfr[j],
                                                                        acc[i][j], 0, 0, 0);
        }
    }
#pragma unroll
    for (int i = 0; i < 4; i++)
#pragma unroll
        for (int r = 0; r < 4; r++) {
            int m = mw + i * 16 + q * 4 + r;
            int orow = rows_s[m];
            if (orow >= 0) {
                float* op = out + (size_t)orow * OUTD + n0 + nw + cc;
#pragma unroll
                for (int j = 0; j < 4; j++) op[j * 16] = acc[i][j][r] + bias[j];
            }
        }
}

// ---------------- fallback GEMMs (round-2, ws too small) ----------------
__global__ __launch_bounds__(256, 2) void gemm1_fb(
    const float* __restrict__ z, const float* __restrict__ W1,
    const float* __restrict__ b1, const int* __restrict__ tstart,
    const int* __restrict__ tcnt, const int* __restrict__ perm,
    __hip_bfloat16* __restrict__ H) {
    int e = blockIdx.y;
    int tc = tcnt[e];
    if (tc == 0) return;
    int ts = tstart[e];
    int n0 = blockIdx.x * TN;
    __shared__ __align__(16) __hip_bfloat16 Bs[(ZD / 8) * TN * 8];
    __shared__ int rows_s[TM];
    int tid = threadIdx.x;
    const float* W = W1 + (size_t)e * ZD * HID;
#pragma unroll
    for (int i = 0; i < 2; ++i) {
        int ko = i * 8 + (tid >> 5);
        int n = tid & 31;
        union { bf16x8 v8; __hip_bfloat16 h[8]; } u;
#pragma unroll
        for (int j = 0; j < 8; ++j)
            u.h[j] = __float2bfloat16(W[(size_t)(ko * 8 + j) * HID + n0 + n]);
        *(bf16x8*)((char*)Bs + (size_t)(ko * TN + n) * 16) = u.v8;
    }
    int lane = tid & 63, wave = tid >> 6;
    int mw = wave * 16;
    int cc = lane & 15, q = lane >> 4;
    float bias0 = b1[(size_t)e * HID + n0 + cc];
    float bias1 = b1[(size_t)e * HID + n0 + 16 + cc];
    __syncthreads();
    for (int mi = 0; mi < tc; ++mi) {
        int mt = ts + mi;
        __syncthreads();
        if (tid < TM) rows_s[tid] = perm[mt * TM + tid];
        __syncthreads();
        int arow = rows_s[mw + cc];
        const float* zp = z + (size_t)(arow < 0 ? 0 : arow) * ZD + q * 8;
        f32x4 acc0 = {0.f, 0.f, 0.f, 0.f}, acc1 = acc0;
#pragma unroll
        for (int s = 0; s < ZD / 32; ++s) {
            float4 v0 = ((const float4*)(zp + s * 32))[0];
            float4 v1 = ((const float4*)(zp + s * 32))[1];
            float v[8] = {v0.x, v0.y, v0.z, v0.w, v1.x, v1.y, v1.z, v1.w};
            union { bf16x8 v8; __hip_bfloat16 h[8]; } u;
#pragma unroll
            for (int j = 0; j < 8; ++j)
                u.h[j] = __float2bfloat16(arow < 0 ? 0.f : v[j]);
            bf16x8 b0 = *(const bf16x8*)((char*)Bs + (size_t)((s * 4 + q) * TN + cc) * 16);
            bf16x8 b1v = *(const bf16x8*)((char*)Bs + (size_t)((s * 4 + q) * TN + 16 + cc) * 16);
            acc0 = __builtin_amdgcn_mfma_f32_16x16x32_bf16(u.v8, b0, acc0, 0, 0, 0);
            acc1 = __builtin_amdgcn_mfma_f32_16x16x32_bf16(u.v8, b1v, acc1, 0, 0, 0);
        }
#pragma unroll
        for (int r = 0; r < 4; ++r) {
            int m = mw + q * 4 + r;
            size_t hb = (size_t)(mt * TM + m) * HID + n0;
            H[hb + cc] = __float2bfloat16(fmaxf(acc0[r] + bias0, 0.f));
            H[hb + 16 + cc] = __float2bfloat16(fmaxf(acc1[r] + bias1, 0.f));
        }
    }
}

__global__ __launch_bounds__(256, 2) void gemm2_fb(
    const __hip_bfloat16* __restrict__ H, const float* __restrict__ W2,
    const float* __restrict__ b2, const int* __restrict__ tstart,
    const int* __restrict__ tcnt, const int* __restrict__ perm,
    float* __restrict__ out) {
    int e = blockIdx.y;
    int tc = tcnt[e];
    if (tc == 0) return;
    int ts = tstart[e];
    int n0 = blockIdx.x * TN;
    __shared__ __align__(16) __hip_bfloat16 Bs[(HID / 8) * TN * 8];
    __shared__ int rows_s[TM];
    int tid = threadIdx.x;
    const float* W = W2 + (size_t)e * HID * OUTD;
#pragma unroll 4
    for (int i = 0; i < 16; ++i) {
        int ko = i * 8 + (tid >> 5);
        int n = tid & 31;
        union { bf16x8 v8; __hip_bfloat16 h[8]; } u;
#pragma unroll
        for (int j = 0; j < 8; ++j)
            u.h[j] = __float2bfloat16(W[(size_t)(ko * 8 + j) * OUTD + n0 + n]);
        *(bf16x8*)((char*)Bs + (size_t)(ko * TN + n) * 16) = u.v8;
    }
    int lane = tid & 63, wave = tid >> 6;
    int mw = wave * 16;
    int cc = lane & 15, q = lane >> 4;
    float bias0 = b2[(size_t)e * OUTD + n0 + cc];
    float bias1 = b2[(size_t)e * OUTD + n0 + 16 + cc];
    __syncthreads();
    for (int mi = 0; mi < tc; ++mi) {
        int mt = ts + mi;
        __syncthreads();
        if (tid < TM) rows_s[tid] = perm[mt * TM + tid];
        __syncthreads();
        const __hip_bfloat16* Ab = H + (size_t)(mt * TM + mw + cc) * HID + q * 8;
        f32x4 acc0 = {0.f, 0.f, 0.f, 0.f}, acc1 = acc0;
#pragma unroll 8
        for (int s = 0; s < HID / 32; ++s) {
            bf16x8 af = *(const bf16x8*)(Ab + s * 32);
            bf16x8 b0 = *(const bf16x8*)((char*)Bs + (size_t)((s * 4 + q) * TN + cc) * 16);
            bf16x8 b1v = *(const bf16x8*)((char*)Bs + (size_t)((s * 4 + q) * TN + 16 + cc) * 16);
            acc0 = __builtin_amdgcn_mfma_f32_16x16x32_bf16(af, b0, acc0, 0, 0, 0);
            acc1 = __builtin_amdgcn_mfma_f32_16x16x32_bf16(af, b1v, acc1, 0, 0, 0);
        }
#pragma unroll
        for (int r = 0; r < 4; ++r) {
            int m = mw + q * 4 + r;
            int orow = rows_s[m];
            if (orow >= 0) {
                size_t ob = (size_t)orow * OUTD + n0;
                out[ob + cc] = acc0[r] + bias0;
                out[ob + 16 + cc] = acc1[r] + bias1;
            }
        }
    }
}

extern "C" void kernel_launch(void* const* d_in, const int* in_sizes, int n_in,
                              void* d_out, int out_size, void* d_ws, size_t ws_size,
                              hipStream_t stream) {
    const float* z  = (const float*)d_in[0];
    const float* W1 = (const float*)d_in[1];
    const float* b1 = (const float*)d_in[2];
    const float* W2 = (const float*)d_in[3];
    const float* b2 = (const float*)d_in[4];
    float* out = (float*)d_out;

    char* ws = (char*)d_ws;
    int* counts = (int*)ws;
    int* ntl    = (int*)(ws + 64);
    int* tstart = (int*)(ws + 128);
    int* tcnt   = (int*)(ws + 192);
    int* texp   = (int*)(ws + 256);
    int* perm   = (int*)(ws + 512);

    const size_t NEED = 59322880ull;
    hipMemsetAsync(counts, 0, 64, stream);

    if (ws_size >= NEED) {
        int* bucket = (int*)(ws + 12800);
        __hip_bfloat16* zb  = (__hip_bfloat16*)(ws + 78336);
        __hip_bfloat16* Hb  = (__hip_bfloat16*)(ws + 602624);
        __hip_bfloat16* W1T = (__hip_bfloat16*)(ws + 6894080);
        __hip_bfloat16* W2T = (__hip_bfloat16*)(ws + 8991232);

        hipLaunchKernelGGL(route_kernel, dim3(BATCH / 4), dim3(256), 0, stream,
                           z, counts, bucket);
        hipLaunchKernelGGL(scan_kernel, dim3(1), dim3(256), 0, stream,
                           counts, ntl, tstart, tcnt, texp, perm, bucket, TMG);
        hipLaunchKernelGGL(convz_kernel, dim3(BATCH * ZD / 1024), dim3(256), 0, stream,
                           z, zb);
        hipLaunchKernelGGL(trans_kernel, dim3(HID / 64, ZD / 64, NEXP), dim3(256), 0,
                           stream, W1, W1T, ZD, HID);
        hipLaunchKernelGGL(trans_kernel, dim3(OUTD / 64, HID / 64, NEXP), dim3(256), 0,
                           stream, W2, W2T, HID, OUTD);
        hipLaunchKernelGGL(gemm1_fast, dim3(HID / TNG, MAXTF), dim3(256), 0, stream,
                           zb, W1T, b1, ntl, texp, perm, Hb);
        hipLaunchKernelGGL(gemm2_fast, dim3(OUTD / TNG, MAXTF), dim3(256), 0, stream,
                           Hb, W2T, b2, ntl, texp, perm, out);
    } else {
        int* bucket = (int*)(ws + 10752);
        __hip_bfloat16* Hb = (__hip_bfloat16*)(ws + 76288);

        hipLaunchKernelGGL(route_kernel, dim3(BATCH / 4), dim3(256), 0, stream,
                           z, counts, bucket);
        hipLaunchKernelGGL(scan_kernel, dim3(1), dim3(256), 0, stream,
                           counts, ntl, tstart, tcnt, texp, perm, bucket, TM);
        hipLaunchKernelGGL(gemm1_fb, dim3(HID / TN, NEXP), dim3(256), 0, stream,
                           z, W1, b1, tstart, tcnt, perm, Hb);
        hipLaunchKernelGGL(gemm2_fb, dim3(OUTD / TN, NEXP), dim3(256), 0, stream,
                           Hb, W2, b2, tstart, tcnt, perm, out);
    }
}

// Round 4
// 215.325 us; speedup vs baseline: 1.2760x; 1.0993x over previous
//
#include <hip/hip_runtime.h>
#include <hip/hip_bf16.h>

// StochasticEnsemble: hard-routed 8-expert MLP.
// Round 4: (a) trans_kernel rewritten to b128-both-sides XOR-chunk LDS
// transpose (conflict-free by construction), (b) route fuses z->bf16 convert
// and uses two-level atomics, (c) dead fallback removed (ws_size = 384 MiB
// proven by the harness's 402 MB 0xAA fill).
// Fast GEMMs (m97 shape, 128x128 tile, BK=64) unchanged from round 3.

#define BATCH 2048
#define ZD 128
#define HID 1024
#define OUTD 3072
#define NEXP 8

#define TMG 128
#define TNG 128
#define BKG 64
#define MAXTF 24          // max 128-row M-tiles: 2048/128 + 8 partials <= 24

typedef short bf16x8 __attribute__((ext_vector_type(8)));   // 8 bf16 = 4 VGPRs
typedef float f32x4 __attribute__((ext_vector_type(4)));

// ---- workspace byte layout (ws_size = 384 MiB, needs 59.4 MB) ----
// 0        counts[8]
// 64       ntl[1]
// 128      texp[24]
// 256      perm[3072]               -> ends 12544
// 12544    bucket[8*2048]           -> ends 78080
// 78080    zb bf16 [2048*128]       -> ends 602368
// 602368   Hb bf16 [3072*1024]      -> ends 6893824
// 6893824  W1T bf16 [8*1024*128]    -> ends 8990976
// 8990976  W2T bf16 [8*3072*1024]   -> ends 59322624

// Route + convert: 8 threads per sample. Each thread reads 16 f32 (64 B
// contiguous), sums floor(|.|*1000) (integral fp32, exact), converts to bf16
// and writes 32 B. Hash: 3-level shfl within the 8-lane group. Two-level
// atomics: LDS histogram, then one global atomicAdd per expert per block.
__global__ __launch_bounds__(256) void route_kernel(const float* __restrict__ z,
                                                    __hip_bfloat16* __restrict__ zb,
                                                    int* counts, int* bucket) {
    __shared__ int lcnt[NEXP];
    __shared__ int gbase[NEXP];
    int t = threadIdx.x;
    if (t < NEXP) lcnt[t] = 0;
    __syncthreads();

    int s = blockIdx.x * 32 + (t >> 3);          // sample
    int li = t & 7;                               // lane-in-sample
    const float* zp = z + (size_t)s * ZD + li * 16;
    float sum = 0.f;
    union { bf16x8 v8; __hip_bfloat16 h[8]; } u0, u1;
#pragma unroll
    for (int i = 0; i < 4; i++) {
        float4 v = ((const float4*)zp)[i];
        sum += floorf(fabsf(v.x) * 1000.0f) + floorf(fabsf(v.y) * 1000.0f) +
               floorf(fabsf(v.z) * 1000.0f) + floorf(fabsf(v.w) * 1000.0f);
        __hip_bfloat16* dst = (i < 2) ? &u0.h[i * 4] : &u1.h[(i - 2) * 4];
        dst[0] = __float2bfloat16(v.x);
        dst[1] = __float2bfloat16(v.y);
        dst[2] = __float2bfloat16(v.z);
        dst[3] = __float2bfloat16(v.w);
    }
    bf16x8* zo = (bf16x8*)(zb + (size_t)s * ZD + li * 16);
    zo[0] = u0.v8;
    zo[1] = u1.v8;

    sum += __shfl_down(sum, 4);
    sum += __shfl_down(sum, 2);
    sum += __shfl_down(sum, 1);
    int e = 0, lpos = 0;
    if (li == 0) {
        e = ((int)sum) & 7;
        lpos = atomicAdd(&lcnt[e], 1);
    }
    __syncthreads();
    if (t < NEXP) gbase[t] = atomicAdd(&counts[t], lcnt[t]);
    __syncthreads();
    if (li == 0) bucket[e * BATCH + gbase[e] + lpos] = s;
}

__global__ void scan_kernel(const int* __restrict__ counts, int* ntl,
                            int* texp, int* perm, const int* __restrict__ bucket) {
    __shared__ int soff[NEXP + 1];
    __shared__ int scnt[NEXP];
    if (threadIdx.x == 0) {
        int o = 0;
        for (int e = 0; e < NEXP; e++) {
            scnt[e] = counts[e];
            soff[e] = o;
            o += (scnt[e] + TMG - 1) & ~(TMG - 1);
        }
        soff[NEXP] = o;
        *ntl = o / TMG;
    }
    __syncthreads();
    int total = soff[NEXP];
    for (int r = threadIdx.x; r < total; r += blockDim.x) {
        int e = 0;
        while (r >= soff[e + 1]) e++;
        int i = r - soff[e];
        perm[r] = (i < scnt[e]) ? bucket[e * BATCH + i] : -1;
        if ((r & (TMG - 1)) == 0) texp[r / TMG] = e;
    }
}

// W[e][K][N] f32 (n-contig) -> WT[e][N][K] bf16 (k-contig).
// Tile 128k x 64n. LDS chunk layout: addr16B(n,c) = n*16 + (c ^ (n&7)).
// Both ds_write_b128 and ds_read_b128 hit all 8 16B-columns balanced ->
// conflict-free. Global loads 256 B-coalesced, global stores 64 B-grouped.
__global__ __launch_bounds__(256) void trans_kernel(const float* __restrict__ W,
                                                    __hip_bfloat16* __restrict__ WT,
                                                    int K, int N) {
    int e = blockIdx.z;
    int n0 = blockIdx.x * 64;
    int k0 = blockIdx.y * 128;
    const float* Wp = W + (size_t)e * K * N;
    __hip_bfloat16* Op = WT + (size_t)e * N * K;
    __shared__ __align__(16) __hip_bfloat16 Ts[64 * 16 * 8];   // 16 KB

    int t = threadIdx.x;
    int nn = (t & 15) * 4;          // 4 consecutive n
    int kb = (t >> 4) * 8;          // 8 consecutive k
    int c = t >> 4;                 // k-chunk index 0..15

    float4 v[8];
#pragma unroll
    for (int i = 0; i < 8; i++)
        v[i] = *(const float4*)(Wp + (size_t)(k0 + kb + i) * N + n0 + nn);

#pragma unroll
    for (int j = 0; j < 4; j++) {
        union { bf16x8 v8; __hip_bfloat16 h[8]; } u;
        float* f = (float*)v;
#pragma unroll
        for (int i = 0; i < 8; i++) u.h[i] = __float2bfloat16(f[i * 4 + j]);
        int n = nn + j;
        *(bf16x8*)(Ts + ((size_t)n * 16 + (c ^ (n & 7))) * 8) = u.v8;
    }
    __syncthreads();

    int n = t >> 2;
#pragma unroll
    for (int p = 0; p < 4; p++) {
        int cd = p * 4 + (t & 3);
        bf16x8 val = *(const bf16x8*)(Ts + ((size_t)n * 16 + (cd ^ (n & 7))) * 8);
        *(bf16x8*)(Op + (size_t)(n0 + n) * K + k0 + cd * 8) = val;
    }
}

// ---------------- fast GEMMs (m97 shape) ----------------
// LDS tile layout: 16B chunk c of row r stored at elem ((r*8) + (c ^ (r&7)))*8.

__global__ __launch_bounds__(256, 3) void gemm1_fast(
    const __hip_bfloat16* __restrict__ zb, const __hip_bfloat16* __restrict__ W1T,
    const float* __restrict__ b1, const int* __restrict__ ntl,
    const int* __restrict__ texp, const int* __restrict__ perm,
    __hip_bfloat16* __restrict__ H) {
    int mt = blockIdx.y;
    if (mt >= *ntl) return;
    int e = texp[mt];
    int n0 = blockIdx.x * TNG;

    __shared__ __align__(16) __hip_bfloat16 As[TMG * BKG];
    __shared__ __align__(16) __hip_bfloat16 Bs[TNG * BKG];
    __shared__ int rows_s[TMG];

    int tid = threadIdx.x;
    if (tid < TMG) rows_s[tid] = perm[mt * TMG + tid];
    __syncthreads();

    int lane = tid & 63, wave = tid >> 6;
    int cc = lane & 15, q = lane >> 4;
    int mw = (wave >> 1) * 64, nw = (wave & 1) * 64;

    int sr = tid >> 3, sc = tid & 7;
    int wbase = sr * 64 + (sc ^ (sr & 7)) * 8;     // + p*2048
    const __hip_bfloat16* Bg = W1T + ((size_t)e * HID + n0 + sr) * ZD + sc * 8;
    const __hip_bfloat16* Arp[4];
#pragma unroll
    for (int p = 0; p < 4; p++) {
        int r = rows_s[p * 32 + sr];
        if (r < 0) r = 0;
        Arp[p] = zb + (size_t)r * ZD + sc * 8;
    }

    int A0 = (mw + cc) * 64, B0 = (nw + cc) * 64;
    int X0 = (q ^ (cc & 7)) * 8, X1 = ((4 + q) ^ (cc & 7)) * 8;

    float bias[4];
#pragma unroll
    for (int j = 0; j < 4; j++) bias[j] = b1[(size_t)e * HID + n0 + nw + j * 16 + cc];

    f32x4 zero4 = {0.f, 0.f, 0.f, 0.f};
    f32x4 acc[4][4];
#pragma unroll
    for (int i = 0; i < 4; i++)
#pragma unroll
        for (int j = 0; j < 4; j++) acc[i][j] = zero4;

    bf16x8 ga[4], gb[4];
#pragma unroll
    for (int p = 0; p < 4; p++) {
        ga[p] = *(const bf16x8*)(Arp[p]);
        gb[p] = *(const bf16x8*)(Bg + (size_t)p * 32 * ZD);
    }
#pragma unroll
    for (int it = 0; it < ZD / BKG; ++it) {
        __syncthreads();
#pragma unroll
        for (int p = 0; p < 4; p++) {
            *(bf16x8*)(As + wbase + p * 2048) = ga[p];
            *(bf16x8*)(Bs + wbase + p * 2048) = gb[p];
        }
        __syncthreads();
        if (it + 1 < ZD / BKG) {
#pragma unroll
            for (int p = 0; p < 4; p++) {
                ga[p] = *(const bf16x8*)(Arp[p] + (it + 1) * BKG);
                gb[p] = *(const bf16x8*)(Bg + (size_t)p * 32 * ZD + (it + 1) * BKG);
            }
        }
#pragma unroll
        for (int kh = 0; kh < 2; ++kh) {
            int X = kh ? X1 : X0;
            bf16x8 af[4], bfr[4];
#pragma unroll
            for (int i = 0; i < 4; i++) af[i] = *(const bf16x8*)(As + A0 + i * 1024 + X);
#pragma unroll
            for (int j = 0; j < 4; j++) bfr[j] = *(const bf16x8*)(Bs + B0 + j * 1024 + X);
#pragma unroll
            for (int i = 0; i < 4; i++)
#pragma unroll
                for (int j = 0; j < 4; j++)
                    acc[i][j] = __builtin_amdgcn_mfma_f32_16x16x32_bf16(af[i], bfr[j],
                                                                        acc[i][j], 0, 0, 0);
        }
    }
#pragma unroll
    for (int i = 0; i < 4; i++)
#pragma unroll
        for (int r = 0; r < 4; r++) {
            int m = mw + i * 16 + q * 4 + r;
            __hip_bfloat16* hp = H + (size_t)(mt * TMG + m) * HID + n0 + nw + cc;
#pragma unroll
            for (int j = 0; j < 4; j++)
                hp[j * 16] = __float2bfloat16(fmaxf(acc[i][j][r] + bias[j], 0.f));
        }
}

__global__ __launch_bounds__(256, 3) void gemm2_fast(
    const __hip_bfloat16* __restrict__ H, const __hip_bfloat16* __restrict__ W2T,
    const float* __restrict__ b2, const int* __restrict__ ntl,
    const int* __restrict__ texp, const int* __restrict__ perm,
    float* __restrict__ out) {
    int mt = blockIdx.y;
    if (mt >= *ntl) return;
    int e = texp[mt];
    int n0 = blockIdx.x * TNG;

    __shared__ __align__(16) __hip_bfloat16 As[TMG * BKG];
    __shared__ __align__(16) __hip_bfloat16 Bs[TNG * BKG];
    __shared__ int rows_s[TMG];

    int tid = threadIdx.x;
    if (tid < TMG) rows_s[tid] = perm[mt * TMG + tid];

    int lane = tid & 63, wave = tid >> 6;
    int cc = lane & 15, q = lane >> 4;
    int mw = (wave >> 1) * 64, nw = (wave & 1) * 64;

    int sr = tid >> 3, sc = tid & 7;
    int wbase = sr * 64 + (sc ^ (sr & 7)) * 8;     // + p*2048
    const __hip_bfloat16* Ag = H + ((size_t)mt * TMG + sr) * HID + sc * 8;
    const __hip_bfloat16* Bg = W2T + ((size_t)e * OUTD + n0 + sr) * HID + sc * 8;

    int A0 = (mw + cc) * 64, B0 = (nw + cc) * 64;
    int X0 = (q ^ (cc & 7)) * 8, X1 = ((4 + q) ^ (cc & 7)) * 8;

    float bias[4];
#pragma unroll
    for (int j = 0; j < 4; j++) bias[j] = b2[(size_t)e * OUTD + n0 + nw + j * 16 + cc];

    f32x4 zero4 = {0.f, 0.f, 0.f, 0.f};
    f32x4 acc[4][4];
#pragma unroll
    for (int i = 0; i < 4; i++)
#pragma unroll
        for (int j = 0; j < 4; j++) acc[i][j] = zero4;

    bf16x8 ga[4], gb[4];
#pragma unroll
    for (int p = 0; p < 4; p++) {
        ga[p] = *(const bf16x8*)(Ag + (size_t)p * 32 * HID);
        gb[p] = *(const bf16x8*)(Bg + (size_t)p * 32 * HID);
    }
    for (int it = 0; it < HID / BKG; ++it) {
        __syncthreads();
#pragma unroll
        for (int p = 0; p < 4; p++) {
            *(bf16x8*)(As + wbase + p * 2048) = ga[p];
            *(bf16x8*)(Bs + wbase + p * 2048) = gb[p];
        }
        __syncthreads();
        if (it + 1 < HID / BKG) {
            int k1 = (it + 1) * BKG;
#pragma unroll
            for (int p = 0; p < 4; p++) {
                ga[p] = *(const bf16x8*)(Ag + (size_t)p * 32 * HID + k1);
                gb[p] = *(const bf16x8*)(Bg + (size_t)p * 32 * HID + k1);
            }
        }
#pragma unroll
        for (int kh = 0; kh < 2; ++kh) {
            int X = kh ? X1 : X0;
            bf16x8 af[4], bfr[4];
#pragma unroll
            for (int i = 0; i < 4; i++) af[i] = *(const bf16x8*)(As + A0 + i * 1024 + X);
#pragma unroll
            for (int j = 0; j < 4; j++) bfr[j] = *(const bf16x8*)(Bs + B0 + j * 1024 + X);
#pragma unroll
            for (int i = 0; i < 4; i++)
#pragma unroll
                for (int j = 0; j < 4; j++)
                    acc[i][j] = __builtin_amdgcn_mfma_f32_16x16x32_bf16(af[i], bfr[j],
                                                                        acc[i][j], 0, 0, 0);
        }
    }
#pragma unroll
    for (int i = 0; i < 4; i++)
#pragma unroll
        for (int r = 0; r < 4; r++) {
            int m = mw + i * 16 + q * 4 + r;
            int orow = rows_s[m];
            if (orow >= 0) {
                float* op = out + (size_t)orow * OUTD + n0 + nw + cc;
#pragma unroll
                for (int j = 0; j < 4; j++) op[j * 16] = acc[i][j][r] + bias[j];
            }
        }
}

extern "C" void kernel_launch(void* const* d_in, const int* in_sizes, int n_in,
                              void* d_out, int out_size, void* d_ws, size_t ws_size,
                              hipStream_t stream) {
    const float* z  = (const float*)d_in[0];
    const float* W1 = (const float*)d_in[1];
    const float* b1 = (const float*)d_in[2];
    const float* W2 = (const float*)d_in[3];
    const float* b2 = (const float*)d_in[4];
    float* out = (float*)d_out;

    char* ws = (char*)d_ws;
    int* counts = (int*)ws;
    int* ntl    = (int*)(ws + 64);
    int* texp   = (int*)(ws + 128);
    int* perm   = (int*)(ws + 256);
    int* bucket = (int*)(ws + 12544);
    __hip_bfloat16* zb  = (__hip_bfloat16*)(ws + 78080);
    __hip_bfloat16* Hb  = (__hip_bfloat16*)(ws + 602368);
    __hip_bfloat16* W1T = (__hip_bfloat16*)(ws + 6893824);
    __hip_bfloat16* W2T = (__hip_bfloat16*)(ws + 8990976);

    hipMemsetAsync(counts, 0, 64, stream);
    hipLaunchKernelGGL(route_kernel, dim3(BATCH / 32), dim3(256), 0, stream,
                       z, zb, counts, bucket);
    hipLaunchKernelGGL(scan_kernel, dim3(1), dim3(256), 0, stream,
                       counts, ntl, texp, perm, bucket);
    hipLaunchKernelGGL(trans_kernel, dim3(HID / 64, ZD / 128, NEXP), dim3(256), 0,
                       stream, W1, W1T, ZD, HID);
    hipLaunchKernelGGL(trans_kernel, dim3(OUTD / 64, HID / 128, NEXP), dim3(256), 0,
                       stream, W2, W2T, HID, OUTD);
    hipLaunchKernelGGL(gemm1_fast, dim3(HID / TNG, MAXTF), dim3(256), 0, stream,
                       zb, W1T, b1, ntl, texp, perm, Hb);
    hipLaunchKernelGGL(gemm2_fast, dim3(OUTD / TNG, MAXTF), dim3(256), 0, stream,
                       Hb, W2T, b2, ntl, texp, perm, out);
}